// Round 9
// baseline (393.002 us; speedup 1.0000x reference)
//
#include <hip/hip_runtime.h>
#include <hip/hip_bf16.h>

// Problem constants (fixed by the reference module)
#define D_MODEL 256
#define NHEAD   8
#define NLVL    4
#define NPTS    4
#define CH      32           // D/NH
#define QTOT    2048
#define BS      8
#define LVTOT   21760        // 128*128 + 64*64 + 32*32 + 16*16
#define KDIM    256

typedef __attribute__((ext_vector_type(8))) short bf16x8;
typedef __attribute__((ext_vector_type(4))) float f32x4;

__device__ inline float bf_lo(unsigned u) { unsigned t = u << 16; float f; __builtin_memcpy(&f, &t, 4); return f; }
__device__ inline float bf_hi(unsigned u) { unsigned t = u & 0xffff0000u; float f; __builtin_memcpy(&f, &t, 4); return f; }
__device__ inline float bfu2f(unsigned short s) { unsigned t = (unsigned)s << 16; float f; __builtin_memcpy(&f, &t, 4); return f; }
__device__ inline unsigned short f2bfu(float f) { __hip_bfloat16 h = __float2bfloat16(f); unsigned short u; __builtin_memcpy(&u, &h, 2); return u; }

#define BK  64
#define LDP 72    // padded LDS row stride for staging (bf16 elements)
#define LDC2 136  // padded LDS row stride for the epilogue C tile (bf16 elems)

// ---------------------------------------------------------------------------
// Fused converts (unchanged from round 8).
// ---------------------------------------------------------------------------
__device__ inline void transpose_W_body(const float* __restrict__ W,
                                        __hip_bfloat16* __restrict__ Wt,
                                        int sh, int blk, int tid) {
    int t = blk * 256 + tid;
    int k = t >> sh, n = t & ((1 << sh) - 1);
    Wt[n * 256 + k] = __float2bfloat16(W[(k << sh) + n]);
}

__global__ __launch_bounds__(256)
void convert_all(const float* __restrict__ q, __hip_bfloat16* __restrict__ qb,
                 const float* __restrict__ Wv, __hip_bfloat16* __restrict__ Wtv,
                 const float* __restrict__ Wo, __hip_bfloat16* __restrict__ Wto,
                 const float* __restrict__ Wa, __hip_bfloat16* __restrict__ Wta) {
    const int bid = blockIdx.x;
    const int tid = threadIdx.x;
    if (bid < 4096) {
        int t = bid * 256 + tid;
        float4 f = ((const float4*)q)[t];
        __hip_bfloat16 h4[4] = {__float2bfloat16(f.x), __float2bfloat16(f.y),
                                __float2bfloat16(f.z), __float2bfloat16(f.w)};
        ((uint2*)qb)[t] = *(const uint2*)h4;
    } else if (bid < 4352) {
        transpose_W_body(Wv, Wtv, 8, bid - 4096, tid);
    } else if (bid < 4608) {
        transpose_W_body(Wo, Wto, 8, bid - 4352, tid);
    } else {
        transpose_W_body(Wa, Wta, 7, bid - 4608, tid);
    }
}

// plain transpose (still needed for W_out, after the fused GEMMs)
__global__ __launch_bounds__(256)
void convert_W(const float* __restrict__ W, __hip_bfloat16* __restrict__ Wt, int sh) {
    int t = blockIdx.x * 256 + threadIdx.x;
    int k = t >> sh, n = t & ((1 << sh) - 1);
    Wt[n * 256 + k] = __float2bfloat16(W[(k << sh) + n]);
}

// ---------------------------------------------------------------------------
// FUSED producer dispatch (unchanged from round 8 — measured 105 µs, no spill).
// ---------------------------------------------------------------------------
__device__ void value_gemm_body(char* smem, int bid_v,
                                const float* __restrict__ A,
                                const __hip_bfloat16* __restrict__ Wt,
                                const float* __restrict__ bias,
                                __hip_bfloat16* __restrict__ v) {
    __hip_bfloat16* As = (__hip_bfloat16*)smem;
    __hip_bfloat16* Bs = (__hip_bfloat16*)(smem + 128 * LDP * 2);
    __hip_bfloat16* Cs = (__hip_bfloat16*)smem;

    const int tid  = threadIdx.x;
    const int lane = tid & 63;
    const int wave = tid >> 6;
    const int wr   = wave >> 1;      // 0..1: row half (64 rows)
    const int wc   = wave & 1;       // 0..1: col half (64 cols)
    const int cb      = (bid_v & 1) * 128;   // column base
    const int rowBase = (bid_v >> 1) * 128;

    const int m0   = lane & 15;
    const int quad = lane >> 4;

    const int ar = tid >> 4;      // 0..15
    const int ac = tid & 15;      // 0..15 (16B chunks)
    const int br = tid >> 3;      // 0..31
    const int bc = tid & 7;       // 0..7  (16B chunks)

    f32x4 acc[4][4] = {};

    for (int kc = 0; kc < KDIM; kc += BK) {
#pragma unroll
        for (int i = 0; i < 8; ++i) {
            const int row = i * 16 + ar;
            float4 f = *(const float4*)(A + (size_t)(rowBase + row) * KDIM + kc + ac * 4);
            __hip_bfloat16 t4[4] = {__float2bfloat16(f.x), __float2bfloat16(f.y),
                                    __float2bfloat16(f.z), __float2bfloat16(f.w)};
            *(uint2*)&As[row * LDP + ac * 4] = *(const uint2*)t4;
        }
#pragma unroll
        for (int i = 0; i < 4; ++i) {
            const int row = i * 32 + br;
            uint4 u = *(const uint4*)(Wt + (size_t)(cb + row) * KDIM + kc + bc * 8);
            *(uint4*)&Bs[row * LDP + bc * 8] = u;
        }
        __syncthreads();

#pragma unroll
        for (int ks = 0; ks < 2; ++ks) {
            bf16x8 af[4], bfv[4];
#pragma unroll
            for (int i = 0; i < 4; ++i)
                af[i] = *(const bf16x8*)&As[(wr * 64 + i * 16 + m0) * LDP + ks * 32 + quad * 8];
#pragma unroll
            for (int j = 0; j < 4; ++j)
                bfv[j] = *(const bf16x8*)&Bs[(wc * 64 + j * 16 + m0) * LDP + ks * 32 + quad * 8];
#pragma unroll
            for (int i = 0; i < 4; ++i)
#pragma unroll
                for (int j = 0; j < 4; ++j)
                    acc[i][j] = __builtin_amdgcn_mfma_f32_16x16x32_bf16(af[i], bfv[j], acc[i][j], 0, 0, 0);
        }
        __syncthreads();
    }

    // epilogue: two 64-row halves through Cs
    const int b = rowBase / LVTOT;
    const int pixBase = rowBase - b * LVTOT;
#pragma unroll
    for (int half = 0; half < 2; ++half) {
        if (wr == half) {
#pragma unroll
            for (int j = 0; j < 4; ++j) {
                const int lcol = wc * 64 + j * 16 + m0;
                const float bv = bias[cb + lcol];
#pragma unroll
                for (int i = 0; i < 4; ++i) {
                    const int lrow = i * 16 + quad * 4;
#pragma unroll
                    for (int r = 0; r < 4; ++r)
                        Cs[(lrow + r) * LDC2 + lcol] = __float2bfloat16(acc[i][j][r] + bv);
                }
            }
        }
        __syncthreads();
        char* dst = (char*)v + (size_t)(b * LVTOT + pixBase + half * 64) * 512 + cb * 2;
        const char* src = (const char*)Cs;
#pragma unroll
        for (int itr = 0; itr < 4; ++itr) {
            const int o = itr * 4096 + tid * 16;
            const int row = o >> 8;
            const int c   = o & 255;
            uint4 val = *(const uint4*)(src + row * (LDC2 * 2) + c);
            *(uint4*)(dst + (size_t)row * 512 + c) = val;
        }
        if (half == 0) __syncthreads();
    }
}

__device__ void offattn_gemm_body(char* smem, int bid,
                                  const __hip_bfloat16* __restrict__ A,
                                  const __hip_bfloat16* __restrict__ Wt_oa,
                                  const float* __restrict__ b_off,
                                  const float* __restrict__ b_attn,
                                  float* __restrict__ off_ws,
                                  float* __restrict__ logits_ws) {
    __hip_bfloat16* As = (__hip_bfloat16*)smem;
    __hip_bfloat16* Bs = (__hip_bfloat16*)(smem + 128 * LDP * 2);

    const int tid  = threadIdx.x;
    const int lane = tid & 63;
    const int wave = tid >> 6;
    const int rowBase = (bid & 127) * 128;   // 128 row blocks
    const int cb      = (bid >> 7) * 128;    // 3 col blocks (N=384)

    const int m0   = lane & 15;
    const int quad = lane >> 4;

    const int br = tid >> 3;      // 0..31
    const int bc = tid & 7;       // 0..7

    f32x4 acc[2][8] = {};

    for (int kc = 0; kc < KDIM; kc += BK) {
#pragma unroll
        for (int i = 0; i < 4; ++i) {
            const int row = i * 32 + br;
            uint4 ua = *(const uint4*)(A     + (size_t)(rowBase + row) * KDIM + kc + bc * 8);
            uint4 ub = *(const uint4*)(Wt_oa + (size_t)(cb + row) * KDIM + kc + bc * 8);
            *(uint4*)&As[row * LDP + bc * 8] = ua;
            *(uint4*)&Bs[row * LDP + bc * 8] = ub;
        }
        __syncthreads();

#pragma unroll
        for (int ks = 0; ks < 2; ++ks) {
            bf16x8 af[2], bfv[8];
#pragma unroll
            for (int i = 0; i < 2; ++i)
                af[i] = *(const bf16x8*)&As[(wave * 32 + i * 16 + m0) * LDP + ks * 32 + quad * 8];
#pragma unroll
            for (int j = 0; j < 8; ++j)
                bfv[j] = *(const bf16x8*)&Bs[(j * 16 + m0) * LDP + ks * 32 + quad * 8];
#pragma unroll
            for (int i = 0; i < 2; ++i)
#pragma unroll
                for (int j = 0; j < 8; ++j)
                    acc[i][j] = __builtin_amdgcn_mfma_f32_16x16x32_bf16(af[i], bfv[j], acc[i][j], 0, 0, 0);
        }
        __syncthreads();
    }

#pragma unroll
    for (int j = 0; j < 8; ++j) {
        const int col = cb + j * 16 + m0;
        const bool isOff = (col < 256);          // block-uniform (cb multiple of 128)
        const float bv = isOff ? b_off[col] : b_attn[col - 256];
#pragma unroll
        for (int i = 0; i < 2; ++i) {
            const int row0 = rowBase + wave * 32 + i * 16 + quad * 4;
#pragma unroll
            for (int r = 0; r < 4; ++r) {
                const float val = acc[i][j][r] + bv;
                if (isOff) off_ws[(size_t)(row0 + r) * 256 + col] = val;
                else       logits_ws[(size_t)(row0 + r) * 128 + (col - 256)] = val;
            }
        }
    }
}

__global__ __launch_bounds__(256, 2)
void fused_gemms(const float* __restrict__ value,
                 const __hip_bfloat16* __restrict__ Wt_v,
                 const float* __restrict__ b_value,
                 __hip_bfloat16* __restrict__ v_ws,
                 const __hip_bfloat16* __restrict__ q_bf,
                 const __hip_bfloat16* __restrict__ Wt_oa,
                 const float* __restrict__ b_off,
                 const float* __restrict__ b_attn,
                 float* __restrict__ off_ws,
                 float* __restrict__ logits_ws) {
    __shared__ __align__(16) char smem[36864];
    const int bid = blockIdx.x;
    if (bid < 384) {
        offattn_gemm_body(smem, bid, q_bf, Wt_oa, b_off, b_attn, off_ws, logits_ws);
    } else {
        value_gemm_body(smem, bid - 384, value, Wt_v, b_value, v_ws);
    }
}

// ---------------------------------------------------------------------------
// Output-projection GEMM (unchanged).
// ---------------------------------------------------------------------------
struct StorePlain {
    float* o;
    int ncol;
    __device__ void operator()(int row, int col, float val) const {
        o[(size_t)row * ncol + col] = val;
    }
};

template <typename Store>
__global__ __launch_bounds__(256, 2)
void gemm_bf16_mfma(const __hip_bfloat16* __restrict__ A,
                    const __hip_bfloat16* __restrict__ Wt,
                    const float* __restrict__ bias, Store store) {
    __shared__ __align__(16) __hip_bfloat16 As[128 * LDP];
    __shared__ __align__(16) __hip_bfloat16 Bs[128 * LDP];

    const int tid  = threadIdx.x;
    const int lane = tid & 63;
    const int wave = tid >> 6;
    const int rowBase = blockIdx.x * 128;
    const int cb = blockIdx.y * 128;

    const int m0   = lane & 15;
    const int quad = lane >> 4;

    const int br = tid >> 3;      // 0..31
    const int bc = tid & 7;       // 0..7

    f32x4 acc[2][8] = {};

    for (int kc = 0; kc < KDIM; kc += BK) {
#pragma unroll
        for (int i = 0; i < 4; ++i) {
            const int row = i * 32 + br;
            uint4 ua = *(const uint4*)(A  + (size_t)(rowBase + row) * KDIM + kc + bc * 8);
            uint4 ub = *(const uint4*)(Wt + (size_t)(cb + row) * KDIM + kc + bc * 8);
            *(uint4*)&As[row * LDP + bc * 8] = ua;
            *(uint4*)&Bs[row * LDP + bc * 8] = ub;
        }
        __syncthreads();

#pragma unroll
        for (int ks = 0; ks < 2; ++ks) {
            bf16x8 af[2], bfv[8];
#pragma unroll
            for (int i = 0; i < 2; ++i)
                af[i] = *(const bf16x8*)&As[(wave * 32 + i * 16 + m0) * LDP + ks * 32 + quad * 8];
#pragma unroll
            for (int j = 0; j < 8; ++j)
                bfv[j] = *(const bf16x8*)&Bs[(j * 16 + m0) * LDP + ks * 32 + quad * 8];
#pragma unroll
            for (int i = 0; i < 2; ++i)
#pragma unroll
                for (int j = 0; j < 8; ++j)
                    acc[i][j] = __builtin_amdgcn_mfma_f32_16x16x32_bf16(af[i], bfv[j], acc[i][j], 0, 0, 0);
        }
        __syncthreads();
    }

#pragma unroll
    for (int j = 0; j < 8; ++j) {
        const int col = cb + j * 16 + m0;
        const float bv = bias[col];
#pragma unroll
        for (int i = 0; i < 2; ++i) {
            const int row0 = rowBase + wave * 32 + i * 16 + quad * 4;
#pragma unroll
            for (int r = 0; r < 4; ++r)
                store(row0 + r, col, acc[i][j][r] + bv);
        }
    }
}

// ---------------------------------------------------------------------------
// Fused softmax + deformable sampling, v3.
// Changes vs v2 (one-variable round):
//  - gather widened: uint2 (8 B = 4 channels) per lane, 8 lanes per 64 B slab;
//    8 load instrs per (q,h) pair instead of 16, identical line traffic.
//  - 2 pairs processed concurrently -> 16 loads in flight (MLP preserved).
//  - idx stored as 16-bit pixel indices (max 21759): idx_s 16->8 KB,
//    LDS 36.5->28.3 KB; __launch_bounds__(256,5) targets 5 blocks/CU.
// ---------------------------------------------------------------------------
__global__ __launch_bounds__(256, 5)
void sample_kernel(const float* __restrict__ off_ws,
                   const float* __restrict__ logits_ws,
                   const float* __restrict__ bbox,
                   const __hip_bfloat16* __restrict__ v,
                   __hip_bfloat16* __restrict__ acc_bf) {
    __shared__ __align__(16) float off_s[8 * 256];        // 8 KB
    __shared__ __align__(16) float attn_s[8 * 128];       // 4 KB
    __shared__ float bbox_s[64];                          // 256 B
    __shared__ __align__(8) unsigned short idx_s[1024 * 4]; // 8 KB (pixel ids)
    __shared__ __align__(8) unsigned short w_s[1024 * 4];   // 8 KB (bf16 w)

    const int tid = threadIdx.x;
    const int b = blockIdx.x & 7;
    const int gq0 = b * QTOT + (blockIdx.x >> 3) * 8;

    // ---- stage off / logits / bbox ----
    const float4* osrc = (const float4*)(off_ws + (size_t)gq0 * 256);
    ((float4*)off_s)[tid] = osrc[tid];
    ((float4*)off_s)[tid + 256] = osrc[tid + 256];
    const float4* lsrc = (const float4*)(logits_ws + (size_t)gq0 * 128);
    ((float4*)attn_s)[tid] = lsrc[tid];
    if (tid < 64) bbox_s[tid] = bbox[(size_t)gq0 * 8 + tid];
    __syncthreads();

    // ---- softmax over 16 per (query, head) ----
    if (tid < 64) {
        int qq = tid >> 3, h = tid & 7;
        float* p = attn_s + qq * 128 + h * 16;
        float m = p[0];
#pragma unroll
        for (int i = 1; i < 16; ++i) m = fmaxf(m, p[i]);
        float e[16], s = 0.f;
#pragma unroll
        for (int i = 0; i < 16; ++i) { e[i] = __expf(p[i] - m); s += e[i]; }
        float inv = 1.f / s;
#pragma unroll
        for (int i = 0; i < 16; ++i) p[i] = e[i] * inv;
    }
    __syncthreads();

    // ---- phase 1: precompute 1024 taps (4 per thread) ----
#pragma unroll
    for (int r = 0; r < 4; ++r) {
        const int tap = tid + r * 256;
        const int qq = tap >> 7, h = (tap >> 4) & 7, l = (tap >> 2) & 3, p = tap & 3;
        const int Wd = 128 >> l;                    // H == W at every level
        const int st = (l == 0) ? 0 : (l == 1) ? 16384 : (l == 2) ? 20480 : 21504;

        const float bx = bbox_s[qq * 8 + l * 2 + 0];
        const float by = bbox_s[qq * 8 + l * 2 + 1];
        const float ox = off_s[qq * 256 + h * 32 + l * 8 + p * 2 + 0];
        const float oy = off_s[qq * 256 + h * 32 + l * 8 + p * 2 + 1];
        const float att = attn_s[qq * 128 + h * 16 + l * 4 + p];

        const float x = bx * (float)Wd + ox - 0.5f;
        const float y = by * (float)Wd + oy - 0.5f;
        const float x0f = floorf(x), y0f = floorf(y);
        const float fx = x - x0f, fy = y - y0f;
        const int x0 = (int)x0f, y0 = (int)y0f;
        const int x1 = x0 + 1, y1 = y0 + 1;
        const bool vx0 = (unsigned)x0 < (unsigned)Wd;
        const bool vx1 = (unsigned)x1 < (unsigned)Wd;
        const bool vy0 = (unsigned)y0 < (unsigned)Wd;
        const bool vy1 = (unsigned)y1 < (unsigned)Wd;
        const int cx0 = min(max(x0, 0), Wd - 1), cx1 = min(max(x1, 0), Wd - 1);
        const int cy0 = min(max(y0, 0), Wd - 1), cy1 = min(max(y1, 0), Wd - 1);

        unsigned short pi[4];
        pi[0] = (unsigned short)(st + cy0 * Wd + cx0);   // pixel index < 21760
        pi[1] = (unsigned short)(st + cy0 * Wd + cx1);
        pi[2] = (unsigned short)(st + cy1 * Wd + cx0);
        pi[3] = (unsigned short)(st + cy1 * Wd + cx1);
        float w0 = (vx0 && vy0) ? (1.f - fx) * (1.f - fy) * att : 0.f;
        float w1 = (vx1 && vy0) ? fx * (1.f - fy) * att : 0.f;
        float w2 = (vx0 && vy1) ? (1.f - fx) * fy * att : 0.f;
        float w3 = (vx1 && vy1) ? fx * fy * att : 0.f;

        *(uint2*)&idx_s[tap * 4] = *(const uint2*)pi;
        unsigned short w4[4] = {f2bfu(w0), f2bfu(w1), f2bfu(w2), f2bfu(w3)};
        *(uint2*)&w_s[tap * 4] = *(const uint2*)w4;
    }
    __syncthreads();

    // ---- phase 2: gather. lane = (g = lane>>3 tap-subgroup, c4 = lane&7
    // channel-quad). 2 pairs per iteration, 16 uint2 loads in flight. ----
    const int lane = tid & 63;
    const int wave = tid >> 6;
    const int g  = lane >> 3;     // 0..7 tap-subgroup
    const int c4 = lane & 7;      // channel quad (4 channels = 8 B)

    const char* vbase = (const char*)v + (size_t)b * LVTOT * 512 + c4 * 8;

    for (int i = 0; i < 8; ++i) {
        const int pairA = wave * 16 + 2 * i;
        const int pairB = pairA + 1;
        const int qqA = pairA >> 3, hhA = pairA & 7;
        const int qqB = pairB >> 3, hhB = pairB & 7;
        const char* slabA = vbase + hhA * 64;
        const char* slabB = vbase + hhB * 64;
        const int tbA = qqA * 128 + hhA * 16;
        const int tbB = qqB * 128 + hhB * 16;

        // tap ids for this lane-group: tbX + g (ts=0) and tbX + 8 + g (ts=1)
        const ushort4 pA0 = *(const ushort4*)&idx_s[(tbA + g) * 4];
        const ushort4 pA1 = *(const ushort4*)&idx_s[(tbA + 8 + g) * 4];
        const ushort4 pB0 = *(const ushort4*)&idx_s[(tbB + g) * 4];
        const ushort4 pB1 = *(const ushort4*)&idx_s[(tbB + 8 + g) * 4];
        const ushort4 wA0 = *(const ushort4*)&w_s[(tbA + g) * 4];
        const ushort4 wA1 = *(const ushort4*)&w_s[(tbA + 8 + g) * 4];
        const ushort4 wB0 = *(const ushort4*)&w_s[(tbB + g) * 4];
        const ushort4 wB1 = *(const ushort4*)&w_s[(tbB + 8 + g) * 4];

        // issue all 16 loads (each uint2 = 4 channels of one corner pixel)
        uint2 uA0 = *(const uint2*)(slabA + ((int)pA0.x << 9));
        uint2 uA1 = *(const uint2*)(slabA + ((int)pA0.y << 9));
        uint2 uA2 = *(const uint2*)(slabA + ((int)pA0.z << 9));
        uint2 uA3 = *(const uint2*)(slabA + ((int)pA0.w << 9));
        uint2 uA4 = *(const uint2*)(slabA + ((int)pA1.x << 9));
        uint2 uA5 = *(const uint2*)(slabA + ((int)pA1.y << 9));
        uint2 uA6 = *(const uint2*)(slabA + ((int)pA1.z << 9));
        uint2 uA7 = *(const uint2*)(slabA + ((int)pA1.w << 9));
        uint2 uB0 = *(const uint2*)(slabB + ((int)pB0.x << 9));
        uint2 uB1 = *(const uint2*)(slabB + ((int)pB0.y << 9));
        uint2 uB2 = *(const uint2*)(slabB + ((int)pB0.z << 9));
        uint2 uB3 = *(const uint2*)(slabB + ((int)pB0.w << 9));
        uint2 uB4 = *(const uint2*)(slabB + ((int)pB1.x << 9));
        uint2 uB5 = *(const uint2*)(slabB + ((int)pB1.y << 9));
        uint2 uB6 = *(const uint2*)(slabB + ((int)pB1.z << 9));
        uint2 uB7 = *(const uint2*)(slabB + ((int)pB1.w << 9));

        float a0 = 0.f, a1 = 0.f, a2 = 0.f, a3 = 0.f;
        float b0 = 0.f, b1 = 0.f, b2 = 0.f, b3 = 0.f;
        {
            float w;
            w = bfu2f(wA0.x); a0 += w * bf_lo(uA0.x); a1 += w * bf_hi(uA0.x); a2 += w * bf_lo(uA0.y); a3 += w * bf_hi(uA0.y);
            w = bfu2f(wA0.y); a0 += w * bf_lo(uA1.x); a1 += w * bf_hi(uA1.x); a2 += w * bf_lo(uA1.y); a3 += w * bf_hi(uA1.y);
            w = bfu2f(wA0.z); a0 += w * bf_lo(uA2.x); a1 += w * bf_hi(uA2.x); a2 += w * bf_lo(uA2.y); a3 += w * bf_hi(uA2.y);
            w = bfu2f(wA0.w); a0 += w * bf_lo(uA3.x); a1 += w * bf_hi(uA3.x); a2 += w * bf_lo(uA3.y); a3 += w * bf_hi(uA3.y);
            w = bfu2f(wA1.x); a0 += w * bf_lo(uA4.x); a1 += w * bf_hi(uA4.x); a2 += w * bf_lo(uA4.y); a3 += w * bf_hi(uA4.y);
            w = bfu2f(wA1.y); a0 += w * bf_lo(uA5.x); a1 += w * bf_hi(uA5.x); a2 += w * bf_lo(uA5.y); a3 += w * bf_hi(uA5.y);
            w = bfu2f(wA1.z); a0 += w * bf_lo(uA6.x); a1 += w * bf_hi(uA6.x); a2 += w * bf_lo(uA6.y); a3 += w * bf_hi(uA6.y);
            w = bfu2f(wA1.w); a0 += w * bf_lo(uA7.x); a1 += w * bf_hi(uA7.x); a2 += w * bf_lo(uA7.y); a3 += w * bf_hi(uA7.y);
            w = bfu2f(wB0.x); b0 += w * bf_lo(uB0.x); b1 += w * bf_hi(uB0.x); b2 += w * bf_lo(uB0.y); b3 += w * bf_hi(uB0.y);
            w = bfu2f(wB0.y); b0 += w * bf_lo(uB1.x); b1 += w * bf_hi(uB1.x); b2 += w * bf_lo(uB1.y); b3 += w * bf_hi(uB1.y);
            w = bfu2f(wB0.z); b0 += w * bf_lo(uB2.x); b1 += w * bf_hi(uB2.x); b2 += w * bf_lo(uB2.y); b3 += w * bf_hi(uB2.y);
            w = bfu2f(wB0.w); b0 += w * bf_lo(uB3.x); b1 += w * bf_hi(uB3.x); b2 += w * bf_lo(uB3.y); b3 += w * bf_hi(uB3.y);
            w = bfu2f(wB1.x); b0 += w * bf_lo(uB4.x); b1 += w * bf_hi(uB4.x); b2 += w * bf_lo(uB4.y); b3 += w * bf_hi(uB4.y);
            w = bfu2f(wB1.y); b0 += w * bf_lo(uB5.x); b1 += w * bf_hi(uB5.x); b2 += w * bf_lo(uB5.y); b3 += w * bf_hi(uB5.y);
            w = bfu2f(wB1.z); b0 += w * bf_lo(uB6.x); b1 += w * bf_hi(uB6.x); b2 += w * bf_lo(uB6.y); b3 += w * bf_hi(uB6.y);
            w = bfu2f(wB1.w); b0 += w * bf_lo(uB7.x); b1 += w * bf_hi(uB7.x); b2 += w * bf_lo(uB7.y); b3 += w * bf_hi(uB7.y);
        }

        // reduce across the 8 tap-subgroups (lane bits 3,4,5)
        a0 += __shfl_xor(a0, 8);  a1 += __shfl_xor(a1, 8);  a2 += __shfl_xor(a2, 8);  a3 += __shfl_xor(a3, 8);
        b0 += __shfl_xor(b0, 8);  b1 += __shfl_xor(b1, 8);  b2 += __shfl_xor(b2, 8);  b3 += __shfl_xor(b3, 8);
        a0 += __shfl_xor(a0, 16); a1 += __shfl_xor(a1, 16); a2 += __shfl_xor(a2, 16); a3 += __shfl_xor(a3, 16);
        b0 += __shfl_xor(b0, 16); b1 += __shfl_xor(b1, 16); b2 += __shfl_xor(b2, 16); b3 += __shfl_xor(b3, 16);
        a0 += __shfl_xor(a0, 32); a1 += __shfl_xor(a1, 32); a2 += __shfl_xor(a2, 32); a3 += __shfl_xor(a3, 32);
        b0 += __shfl_xor(b0, 32); b1 += __shfl_xor(b1, 32); b2 += __shfl_xor(b2, 32); b3 += __shfl_xor(b3, 32);

        if (g == 0) {
            unsigned lo, hi;
            __hip_bfloat16 h2[2];
            h2[0] = __float2bfloat16(a0); h2[1] = __float2bfloat16(a1);
            __builtin_memcpy(&lo, h2, 4);
            h2[0] = __float2bfloat16(a2); h2[1] = __float2bfloat16(a3);
            __builtin_memcpy(&hi, h2, 4);
            uint2 pk; pk.x = lo; pk.y = hi;
            *(uint2*)((char*)acc_bf + ((size_t)(gq0 + qqA) * 256 + hhA * 32 + c4 * 4) * 2) = pk;
            h2[0] = __float2bfloat16(b0); h2[1] = __float2bfloat16(b1);
            __builtin_memcpy(&lo, h2, 4);
            h2[0] = __float2bfloat16(b2); h2[1] = __float2bfloat16(b3);
            __builtin_memcpy(&hi, h2, 4);
            pk.x = lo; pk.y = hi;
            *(uint2*)((char*)acc_bf + ((size_t)(gq0 + qqB) * 256 + hhB * 32 + c4 * 4) * 2) = pk;
        }
    }
}

// ---------------------------------------------------------------------------
extern "C" void kernel_launch(void* const* d_in, const int* in_sizes, int n_in,
                              void* d_out, int out_size, void* d_ws, size_t ws_size,
                              hipStream_t stream) {
    const float* query   = (const float*)d_in[0];
    const float* bbox    = (const float*)d_in[1];
    const float* value   = (const float*)d_in[2];
    const float* W_value = (const float*)d_in[4];
    const float* b_value = (const float*)d_in[5];
    const float* W_off   = (const float*)d_in[6];
    const float* b_off   = (const float*)d_in[7];
    const float* W_attn  = (const float*)d_in[8];
    const float* b_attn  = (const float*)d_in[9];
    const float* W_out   = (const float*)d_in[10];
    const float* b_out   = (const float*)d_in[11];
    float* out = (float*)d_out;

    // workspace layout (total exactly 131,072,000 B)
    char* ws = (char*)d_ws;
    __hip_bfloat16* v_ws  = (__hip_bfloat16*)ws;                               // 89,128,960
    float* off_ws         = (float*)(ws + 89128960);                           // 16,777,216
    float* logits_ws      = (float*)(ws + 89128960 + 16777216);                //  8,388,608
    __hip_bfloat16* acc_bf = (__hip_bfloat16*)(ws + 89128960 + 16777216 + 8388608);      // 8,388,608
    __hip_bfloat16* q_bf   = (__hip_bfloat16*)(ws + 89128960 + 16777216 + 8388608 + 8388608); // 8,388,608

    // Wt tables overlay dead regions (consumed before their region is written)
    __hip_bfloat16* Wt_v    = acc_bf;                  // 131,072 B
    __hip_bfloat16* Wt_off  = acc_bf + 65536;          // 131,072 B
    __hip_bfloat16* Wt_attn = acc_bf + 131072;         //  65,536 B
    __hip_bfloat16* Wt_out  = q_bf;                    // 131,072 B

    const int NQ = BS * QTOT;          // 16384
    const int NVROWS = BS * LVTOT;     // 174080

    // 1. all converts in one dispatch
    convert_all<<<4736, 256, 0, stream>>>(query, q_bf,
                                          W_value, Wt_v,
                                          W_off, Wt_off,
                                          W_attn, Wt_attn);

    // 2. fused producer: off+attn GEMM (384 blocks) + value GEMM (2720 blocks)
    fused_gemms<<<384 + 2 * (NVROWS / 128), 256, 0, stream>>>(
        value, Wt_v, b_value, v_ws,
        q_bf, Wt_off, b_off, b_attn, off_ws, logits_ws);

    // 3. W_out transpose into q_bf region (q_bf dead after step 2)
    convert_W<<<256, 256, 0, stream>>>(W_out, Wt_out, 8);

    // 4. softmax + deformable sampling -> acc_bf
    sample_kernel<<<NQ / 8, 256, 0, stream>>>(off_ws, logits_ws, bbox, v_ws, acc_bf);

    // 5. output projection -> d_out (fp32)
    gemm_bf16_mfma<<<dim3(NQ / 128, 2), 256, 0, stream>>>(
        acc_bf, Wt_out, b_out, StorePlain{out, 256});
}